// Round 1
// 560.588 us; speedup vs baseline: 1.0210x; 1.0210x over previous
//
#include <hip/hip_runtime.h>
#include <math.h>

// GCN 2-layer forward on MI355X — round 6.
//  Change vs round 5: layer-2 feature matrix g stored as bf16 padded to 64
//  cols (128 B rows, cacheline-aligned) -> agg2 gather fetches exactly one
//  line per edge (was 2 lines for misaligned 160 B fp32 rows).
//  agg2 rewritten: one wave per node, edge pair split across wave halves,
//  shuffle log-softmax (no LDS). k_dinv folded into k_bsort, w2t into wprep.

typedef unsigned int uint;
typedef unsigned short ushort_t;
using short8  = __attribute__((ext_vector_type(8))) short;
using float4v = __attribute__((ext_vector_type(4))) float;

__device__ __forceinline__ ushort_t f2bf(float f) {
    uint u = __float_as_uint(f);
    u += 0x7FFFu + ((u >> 16) & 1u);   // RNE
    return (ushort_t)(u >> 16);
}
__device__ __forceinline__ float2 unpack2(uint v) {
    return make_float2(__uint_as_float(v << 16), __uint_as_float(v & 0xFFFF0000u));
}
__device__ __forceinline__ uint pack2(float a, float b) {
    return (uint)f2bf(a) | ((uint)f2bf(b) << 16);
}

// ---------------- bucket counting sort -----------------------------------
// NB = ceil(n/128) buckets (<= 800 for n <= 102400).

__global__ __launch_bounds__(256) void k_bhist(const int* __restrict__ dst,
                                               int* __restrict__ bcnt, int e, int nb) {
    __shared__ int h[800];
    for (int t = threadIdx.x; t < nb; t += 256) h[t] = 0;
    __syncthreads();
    int ibase = blockIdx.x * 2560 + threadIdx.x;
#pragma unroll
    for (int j = 0; j < 10; j++) {
        int i = ibase + j * 256;
        if (i < e) atomicAdd(&h[dst[i] >> 7], 1);
    }
    __syncthreads();
    for (int t = threadIdx.x; t < nb; t += 256) {
        int c = h[t];
        if (c) atomicAdd(&bcnt[t], c);
    }
}

// one block: exclusive scan of nb (<1024) bucket counts
__global__ __launch_bounds__(256) void k_bscan(const int* __restrict__ bcnt, int* __restrict__ bbase,
                                               int* __restrict__ bcur, int* __restrict__ row_ptr,
                                               int nb, int n, int e) {
    __shared__ int sd[256];
    int t = threadIdx.x;
    int base = t * 4;
    int v[4];
#pragma unroll
    for (int j = 0; j < 4; j++) v[j] = (base + j < nb) ? bcnt[base + j] : 0;
    int s0 = v[0], s1 = s0 + v[1], s2 = s1 + v[2], s3 = s2 + v[3];
    sd[t] = s3;
    __syncthreads();
    for (int d = 1; d < 256; d <<= 1) {
        int x = (t >= d) ? sd[t - d] : 0;
        __syncthreads();
        sd[t] += x;
        __syncthreads();
    }
    int excl = sd[t] - s3;
    int pre0 = excl, pre1 = excl + s0, pre2 = excl + s1, pre3 = excl + s2;
    if (base + 0 < nb) { bbase[base + 0] = pre0; bcur[base + 0] = pre0; }
    if (base + 1 < nb) { bbase[base + 1] = pre1; bcur[base + 1] = pre1; }
    if (base + 2 < nb) { bbase[base + 2] = pre2; bcur[base + 2] = pre2; }
    if (base + 3 < nb) { bbase[base + 3] = pre3; bcur[base + 3] = pre3; }
    if (t == 255) bbase[nb] = excl + s3;   // == e
    if (t == 0) row_ptr[n] = e;
}

// partition: packed (dstlocal<<25)|src into bucket regions
__global__ __launch_bounds__(256) void k_part(const int* __restrict__ src, const int* __restrict__ dst,
                                              int* __restrict__ bcur, uint* __restrict__ pbuf,
                                              int e, int nb) {
    __shared__ int h[800];
    __shared__ int base_l[800];
    for (int t = threadIdx.x; t < nb; t += 256) h[t] = 0;
    __syncthreads();
    uint pk[10]; int bk[10]; int lp[10];
    int ibase = blockIdx.x * 2560 + threadIdx.x;
#pragma unroll
    for (int j = 0; j < 10; j++) {
        int i = ibase + j * 256;
        bk[j] = -1;
        if (i < e) {
            int s = src[i], d = dst[i];
            int b = d >> 7;
            bk[j] = b;
            pk[j] = ((uint)(d & 127) << 25) | (uint)s;
            lp[j] = atomicAdd(&h[b], 1);
        }
    }
    __syncthreads();
    for (int t = threadIdx.x; t < nb; t += 256) {
        int c = h[t];
        base_l[t] = c ? atomicAdd(&bcur[t], c) : 0;
    }
    __syncthreads();
#pragma unroll
    for (int j = 0; j < 10; j++) {
        if (bk[j] >= 0) pbuf[base_l[bk[j]] + lp[j]] = pk[j];
    }
}

// per-bucket fine sort: emits dinv, row_ptr, es_src
__global__ __launch_bounds__(256) void k_bsort(const uint* __restrict__ pbuf,
                                               const int* __restrict__ bbase,
                                               float* __restrict__ dinv,
                                               int* __restrict__ row_ptr,
                                               int* __restrict__ es_src, int n) {
    __shared__ int cl[128];
    __shared__ int cur[128];
    const int b = blockIdx.x;
    const int tid = threadIdx.x;
    const int ebeg = bbase[b], eend = bbase[b + 1];
    const int m = eend - ebeg;
    if (tid < 128) cl[tid] = 0;
    __syncthreads();
    for (int i = tid; i < m; i += 256) {
        uint p = pbuf[ebeg + i];
        atomicAdd(&cl[p >> 25], 1);
    }
    __syncthreads();
    int own = (tid < 128) ? cl[tid] : 0;
    for (int d = 1; d < 128; d <<= 1) {
        int v = 0;
        if (tid < 128 && tid >= d) v = cl[tid - d];
        __syncthreads();
        if (tid < 128 && tid >= d) cl[tid] += v;
        __syncthreads();
    }
    if (tid < 128) {
        int excl = cl[tid] - own;
        int node = b * 128 + tid;
        if (node < n) {
            dinv[node] = rsqrtf((float)(own + 1));   // deg incl. self-loop
            row_ptr[node] = ebeg + excl;
        }
        cur[tid] = excl;
    }
    __syncthreads();
    for (int i = tid; i < m; i += 256) {
        uint p = pbuf[ebeg + i];
        int dl = (int)(p >> 25);
        int pos = atomicAdd(&cur[dl], 1);
        es_src[ebeg + pos] = (int)(p & 0x1FFFFFFu);
    }
}

// ---- weight prep (merged) -----------------------------------------------
__global__ __launch_bounds__(256) void k_wprep(const float* __restrict__ W1,
                                               const float* __restrict__ W2,
                                               ushort_t* __restrict__ W1t,
                                               ushort_t* __restrict__ W2t) {
    int idx = blockIdx.x * 256 + threadIdx.x;   // 71680 threads, 280 blocks
    if (idx < 65536) {
        int nn = idx >> 9, k = idx & 511;
        W1t[idx] = f2bf(W1[(size_t)k * 128 + nn]);
    } else {
        int j = idx - 65536;
        if (j < 6144) {
            int c = j >> 7, k = j & 127;
            W2t[j] = (c < 40) ? f2bf(W2[(size_t)k * 40 + c]) : (ushort_t)0;
        }
    }
}

// ---- GEMM1 (MFMA bf16): h'[i] = bf16(dinv[i] * (x @ W1)[i]) -------------
__global__ __launch_bounds__(256) void k_gemm1(const float* __restrict__ x,
                                               const ushort_t* __restrict__ W1t,
                                               const float* __restrict__ dinv,
                                               ushort_t* __restrict__ h, int n) {
    __shared__ ushort_t As[64][72];
    __shared__ ushort_t Bs[128][72];
    const int tid  = threadIdx.x;
    const int w    = tid >> 6, lane = tid & 63;
    const int quad = lane >> 4, l16 = lane & 15;
    const int row0 = blockIdx.x * 64;

    float4v acc[8];
#pragma unroll
    for (int i = 0; i < 8; i++) acc[i] = (float4v)0.f;

    const int ar  = tid >> 2;
    const int akq = (tid & 3) * 16;
    const int br  = tid >> 1;
    const int bkq = (tid & 1) * 32;
    const int agrow = row0 + ar;
    const float* xp0 = &x[(size_t)agrow * 512];
    const ushort_t* wp0 = &W1t[(size_t)br * 512];

    for (int kb = 0; kb < 512; kb += 64) {
#pragma unroll
        for (int j = 0; j < 4; j++) {
            float4 v = make_float4(0.f, 0.f, 0.f, 0.f);
            if (agrow < n) v = *(const float4*)(xp0 + kb + akq + j * 4);
            ushort4 b;
            b.x = f2bf(v.x); b.y = f2bf(v.y); b.z = f2bf(v.z); b.w = f2bf(v.w);
            *(ushort4*)&As[ar][akq + j * 4] = b;
        }
#pragma unroll
        for (int j = 0; j < 8; j++) {
            *(ushort4*)&Bs[br][bkq + j * 4] = *(const ushort4*)(wp0 + kb + bkq + j * 4);
        }
        __syncthreads();
#pragma unroll
        for (int ks = 0; ks < 64; ks += 32) {
            short8 a = *(const short8*)&As[w * 16 + l16][ks + quad * 8];
#pragma unroll
            for (int ct = 0; ct < 8; ct++) {
                short8 b = *(const short8*)&Bs[ct * 16 + l16][ks + quad * 8];
                acc[ct] = __builtin_amdgcn_mfma_f32_16x16x32_bf16(a, b, acc[ct], 0, 0, 0);
            }
        }
        __syncthreads();
    }
#pragma unroll
    for (int r = 0; r < 4; r++) {
        int grow = row0 + w * 16 + quad * 4 + r;
        if (grow >= n) continue;
        float di = dinv[grow];
#pragma unroll
        for (int ct = 0; ct < 8; ct++) {
            int col = ct * 16 + l16;
            h[(size_t)grow * 128 + col] = f2bf(di * acc[ct][r]);
        }
    }
}

// ---- agg1: h1 = bf16(relu(dinv[node]*(h'[node]+Σ h'[src]) + b1)) --------
__global__ __launch_bounds__(256) void k_agg1(const uint* __restrict__ h,
                                              const int* __restrict__ row_ptr,
                                              const int* __restrict__ es_src,
                                              const float* __restrict__ dinv,
                                              const float* __restrict__ b1,
                                              uint* __restrict__ h1, int n) {
    const int tid  = threadIdx.x;
    const int node = blockIdx.x * 4 + (tid >> 6);
    if (node >= n) return;
    const int lane = tid & 63;
    float2 acc = unpack2(h[(size_t)node * 64 + lane]);   // self term
    const int k0 = row_ptr[node], k1 = row_ptr[node + 1];
    int k = k0;
    for (; k + 3 < k1; k += 4) {
        int s0 = es_src[k], s1 = es_src[k + 1], s2 = es_src[k + 2], s3 = es_src[k + 3];
        float2 v0 = unpack2(h[(size_t)s0 * 64 + lane]);
        float2 v1 = unpack2(h[(size_t)s1 * 64 + lane]);
        float2 v2 = unpack2(h[(size_t)s2 * 64 + lane]);
        float2 v3 = unpack2(h[(size_t)s3 * 64 + lane]);
        acc.x += (v0.x + v1.x) + (v2.x + v3.x);
        acc.y += (v0.y + v1.y) + (v2.y + v3.y);
    }
    for (; k < k1; k++) {
        int s = es_src[k];
        float2 v = unpack2(h[(size_t)s * 64 + lane]);
        acc.x += v.x;
        acc.y += v.y;
    }
    const float di = dinv[node];
    float2 bb = *(const float2*)&b1[lane * 2];
    acc.x = di * acc.x + bb.x;
    acc.y = di * acc.y + bb.y;
    acc.x = acc.x > 0.f ? acc.x : 0.f;
    acc.y = acc.y > 0.f ? acc.y : 0.f;
    h1[(size_t)node * 64 + lane] = pack2(acc.x, acc.y);
}

// ---- GEMM2 (MFMA bf16): g[i] = bf16(dinv[i] * (h1 @ W2)[i]), [n,64] pad -
__global__ __launch_bounds__(256) void k_gemm2(const ushort_t* __restrict__ h1,
                                               const ushort_t* __restrict__ W2t,
                                               const float* __restrict__ dinv,
                                               ushort_t* __restrict__ g, int n) {
    __shared__ ushort_t As[64][136];
    __shared__ ushort_t Bs[48][136];
    const int tid  = threadIdx.x;
    const int w    = tid >> 6, lane = tid & 63;
    const int quad = lane >> 4, l16 = lane & 15;
    const int row0 = blockIdx.x * 64;

    {
        int ar = tid >> 2;
        int ak = (tid & 3) * 32;
        int grow = row0 + ar;
#pragma unroll
        for (int j = 0; j < 4; j++) {
            uint4 v = make_uint4(0, 0, 0, 0);
            if (grow < n) v = *(const uint4*)&h1[(size_t)grow * 128 + ak + j * 8];
            *(uint4*)&As[ar][ak + j * 8] = v;
        }
    }
    for (int i = tid; i < 768; i += 256) {
        int row = i >> 4, q = i & 15;
        *(uint4*)&Bs[row][q * 8] = *(const uint4*)&W2t[(size_t)row * 128 + q * 8];
    }
    __syncthreads();

    float4v acc[3];
#pragma unroll
    for (int i = 0; i < 3; i++) acc[i] = (float4v)0.f;
#pragma unroll
    for (int ks = 0; ks < 128; ks += 32) {
        short8 a = *(const short8*)&As[w * 16 + l16][ks + quad * 8];
#pragma unroll
        for (int ct = 0; ct < 3; ct++) {
            short8 b = *(const short8*)&Bs[ct * 16 + l16][ks + quad * 8];
            acc[ct] = __builtin_amdgcn_mfma_f32_16x16x32_bf16(a, b, acc[ct], 0, 0, 0);
        }
    }
#pragma unroll
    for (int r = 0; r < 4; r++) {
        int grow = row0 + w * 16 + quad * 4 + r;
        if (grow >= n) continue;
        float di = dinv[grow];
#pragma unroll
        for (int ct = 0; ct < 3; ct++) {
            int col = ct * 16 + l16;
            g[(size_t)grow * 64 + col] = f2bf(di * acc[ct][r]);
        }
        g[(size_t)grow * 64 + 48 + l16] = (ushort_t)0;   // zero pad cols 48..63
    }
}

// ---- agg2 + bias + log_softmax fused ------------------------------------
// one wave per node; lanes 0-31 handle edge k, lanes 32-63 edge k+1;
// each 32-lane half: lane l holds cols (2l, 2l+1). g rows = 128 B aligned.
__global__ __launch_bounds__(256) void k_agg2(const uint* __restrict__ g,
                                              const int* __restrict__ row_ptr,
                                              const int* __restrict__ es_src,
                                              const float* __restrict__ dinv,
                                              const float* __restrict__ b2,
                                              float* __restrict__ out1,
                                              float* __restrict__ out2, int n) {
    const int tid  = threadIdx.x;
    const int node = blockIdx.x * 4 + (tid >> 6);
    if (node >= n) return;
    const int lane = tid & 63;
    const int half = lane >> 5;
    const int l    = lane & 31;

    float2 acc = make_float2(0.f, 0.f);
    if (half == 0) acc = unpack2(g[(size_t)node * 32 + l]);   // self term
    const int k0 = row_ptr[node], k1 = row_ptr[node + 1];
    int k = k0 + half;
    for (; k + 2 < k1; k += 4) {           // 4 edges in flight per wave
        int s0 = es_src[k], s1 = es_src[k + 2];
        float2 v0 = unpack2(g[(size_t)s0 * 32 + l]);
        float2 v1 = unpack2(g[(size_t)s1 * 32 + l]);
        acc.x += v0.x + v1.x;
        acc.y += v0.y + v1.y;
    }
    for (; k < k1; k += 2) {
        float2 v = unpack2(g[(size_t)es_src[k] * 32 + l]);
        acc.x += v.x;
        acc.y += v.y;
    }
    // combine halves
    acc.x += __shfl_xor(acc.x, 32);
    acc.y += __shfl_xor(acc.y, 32);

    const float di = dinv[node];
    float2 bb = (l < 20) ? *(const float2*)&b2[l * 2] : make_float2(0.f, 0.f);
    float v0 = di * acc.x + bb.x;
    float v1 = di * acc.y + bb.y;

    // log-softmax over the 40 real cols (lanes l<20 of each half)
    float m = (l < 20) ? fmaxf(v0, v1) : -1e30f;
#pragma unroll
    for (int d = 16; d; d >>= 1) m = fmaxf(m, __shfl_xor(m, d));
    float s = (l < 20) ? (expf(v0 - m) + expf(v1 - m)) : 0.f;
#pragma unroll
    for (int d = 16; d; d >>= 1) s += __shfl_xor(s, d);
    float ls = logf(s) + m;

    if (half == 0 && l < 20) {
        *(float2*)&out1[(size_t)node * 40 + l * 2] = make_float2(v0, v1);
        *(float2*)&out2[(size_t)node * 40 + l * 2] = make_float2(v0 - ls, v1 - ls);
    }
}

static inline size_t align4(size_t v) { return (v + 3) & ~(size_t)3; }

extern "C" void kernel_launch(void* const* d_in, const int* in_sizes, int n_in,
                              void* d_out, int out_size, void* d_ws, size_t ws_size,
                              hipStream_t stream) {
    const float* x  = (const float*)d_in[0];
    const int*   ei = (const int*)d_in[1];
    const float* W1 = (const float*)d_in[2];
    const float* b1 = (const float*)d_in[3];
    const float* W2 = (const float*)d_in[4];
    const float* b2 = (const float*)d_in[5];

    const int n = in_sizes[0] / 512;
    const int e = in_sizes[1] / 2;
    const int* src = ei;
    const int* dst = ei + e;
    const int NB = (n + 127) >> 7;           // buckets of 128 nodes (<=800)

    char* p = (char*)d_ws;
    int*      bcnt    = (int*)p;        p += align4(NB) * 4;
    int*      bbase   = (int*)p;        p += align4(NB + 1) * 4;
    int*      bcur    = (int*)p;        p += align4(NB) * 4;
    int*      row_ptr = (int*)p;        p += align4(n + 1) * 4;
    float*    dinv    = (float*)p;      p += align4(n) * 4;
    uint*     pbuf    = (uint*)p;       p += align4(e) * 4;
    int*      es_src  = (int*)p;        p += align4(e) * 4;
    ushort_t* W1t     = (ushort_t*)p;   p += (size_t)128 * 512 * 2;
    ushort_t* W2t     = (ushort_t*)p;   p += (size_t)48 * 128 * 2;
    ushort_t* h       = (ushort_t*)p;   p += (size_t)n * 128 * 2;   // h' bf16; g overlays
    ushort_t* h1      = (ushort_t*)p;   p += (size_t)n * 128 * 2;   // bf16
    ushort_t* g       = h;                                          // [n,64] bf16, 128 B rows
    float*    out1    = (float*)d_out;
    float*    out2    = out1 + (size_t)n * 40;

    const int B = 256;
    const int nblkA = (e + 2559) / 2560;

    // CSR build via 2-level counting sort
    hipMemsetAsync(bcnt, 0, (size_t)NB * 4, stream);
    k_bhist<<<nblkA, B, 0, stream>>>(dst, bcnt, e, NB);
    k_bscan<<<1, 256, 0, stream>>>(bcnt, bbase, bcur, row_ptr, NB, n, e);
    k_part<<<nblkA, B, 0, stream>>>(src, dst, bcur, pbuf, e, NB);
    k_bsort<<<NB, 256, 0, stream>>>(pbuf, bbase, dinv, row_ptr, es_src, n);

    // weights
    k_wprep<<<280, 256, 0, stream>>>(W1, W2, W1t, W2t);

    // layer 1
    k_gemm1<<<(n + 63) / 64, 256, 0, stream>>>(x, W1t, dinv, h, n);
    k_agg1<<<(n + 3) / 4, 256, 0, stream>>>((const uint*)h, row_ptr, es_src, dinv, b1, (uint*)h1, n);

    // layer 2
    k_gemm2<<<(n + 63) / 64, 256, 0, stream>>>(h1, W2t, dinv, g, n);
    k_agg2<<<(n + 3) / 4, 256, 0, stream>>>((const uint*)g, row_ptr, es_src, dinv, b2, out1, out2, n);
}

// Round 2
// 535.061 us; speedup vs baseline: 1.0697x; 1.0477x over previous
//
#include <hip/hip_runtime.h>
#include <math.h>

// GCN 2-layer forward on MI355X — round 7.
//  Change vs round 6: aggregation kernels rewritten with wide gathers.
//   k_agg1: 16 lanes/edge, dwordx4 loads -> 4 edges per VMEM instr, x2 unroll.
//   k_agg2: 8 lanes/edge,  dwordx4 loads -> 8 edges per VMEM instr, x2 unroll.
//   Cross-group shfl_xor reduce once per node. wprep folded into bhist launch.

typedef unsigned int uint;
typedef unsigned short ushort_t;
using short8  = __attribute__((ext_vector_type(8))) short;
using float4v = __attribute__((ext_vector_type(4))) float;

__device__ __forceinline__ ushort_t f2bf(float f) {
    uint u = __float_as_uint(f);
    u += 0x7FFFu + ((u >> 16) & 1u);   // RNE
    return (ushort_t)(u >> 16);
}
__device__ __forceinline__ float2 unpack2(uint v) {
    return make_float2(__uint_as_float(v << 16), __uint_as_float(v & 0xFFFF0000u));
}
__device__ __forceinline__ uint pack2(float a, float b) {
    return (uint)f2bf(a) | ((uint)f2bf(b) << 16);
}
__device__ __forceinline__ void acc8(float* acc, uint4 v) {
    float2 a0 = unpack2(v.x), a1 = unpack2(v.y), a2 = unpack2(v.z), a3 = unpack2(v.w);
    acc[0] += a0.x; acc[1] += a0.y; acc[2] += a1.x; acc[3] += a1.y;
    acc[4] += a2.x; acc[5] += a2.y; acc[6] += a3.x; acc[7] += a3.y;
}

// ---------------- bucket counting sort -----------------------------------
// NB = ceil(n/128) buckets (<= 800 for n <= 102400).
// Fat launch: blocks [0, nblkA) do the dst histogram; blocks >= nblkA do
// weight prep (W1t / W2t bf16 transpose) — independent work, one dispatch.

__global__ __launch_bounds__(256) void k_bhist_wprep(const int* __restrict__ dst,
                                                     int* __restrict__ bcnt, int e, int nb,
                                                     int nblkA,
                                                     const float* __restrict__ W1,
                                                     const float* __restrict__ W2,
                                                     ushort_t* __restrict__ W1t,
                                                     ushort_t* __restrict__ W2t) {
    if (blockIdx.x >= (uint)nblkA) {
        int idx = (blockIdx.x - nblkA) * 256 + threadIdx.x;   // 71680 threads
        if (idx < 65536) {
            int nn = idx >> 9, k = idx & 511;
            W1t[idx] = f2bf(W1[(size_t)k * 128 + nn]);
        } else {
            int j = idx - 65536;
            if (j < 6144) {
                int c = j >> 7, k = j & 127;
                W2t[j] = (c < 40) ? f2bf(W2[(size_t)k * 40 + c]) : (ushort_t)0;
            }
        }
        return;
    }
    __shared__ int h[800];
    for (int t = threadIdx.x; t < nb; t += 256) h[t] = 0;
    __syncthreads();
    int ibase = blockIdx.x * 2560 + threadIdx.x;
#pragma unroll
    for (int j = 0; j < 10; j++) {
        int i = ibase + j * 256;
        if (i < e) atomicAdd(&h[dst[i] >> 7], 1);
    }
    __syncthreads();
    for (int t = threadIdx.x; t < nb; t += 256) {
        int c = h[t];
        if (c) atomicAdd(&bcnt[t], c);
    }
}

// one block: exclusive scan of nb (<1024) bucket counts
__global__ __launch_bounds__(256) void k_bscan(const int* __restrict__ bcnt, int* __restrict__ bbase,
                                               int* __restrict__ bcur, int* __restrict__ row_ptr,
                                               int nb, int n, int e) {
    __shared__ int sd[256];
    int t = threadIdx.x;
    int base = t * 4;
    int v[4];
#pragma unroll
    for (int j = 0; j < 4; j++) v[j] = (base + j < nb) ? bcnt[base + j] : 0;
    int s0 = v[0], s1 = s0 + v[1], s2 = s1 + v[2], s3 = s2 + v[3];
    sd[t] = s3;
    __syncthreads();
    for (int d = 1; d < 256; d <<= 1) {
        int x = (t >= d) ? sd[t - d] : 0;
        __syncthreads();
        sd[t] += x;
        __syncthreads();
    }
    int excl = sd[t] - s3;
    int pre0 = excl, pre1 = excl + s0, pre2 = excl + s1, pre3 = excl + s2;
    if (base + 0 < nb) { bbase[base + 0] = pre0; bcur[base + 0] = pre0; }
    if (base + 1 < nb) { bbase[base + 1] = pre1; bcur[base + 1] = pre1; }
    if (base + 2 < nb) { bbase[base + 2] = pre2; bcur[base + 2] = pre2; }
    if (base + 3 < nb) { bbase[base + 3] = pre3; bcur[base + 3] = pre3; }
    if (t == 255) bbase[nb] = excl + s3;   // == e
    if (t == 0) row_ptr[n] = e;
}

// partition: packed (dstlocal<<25)|src into bucket regions
__global__ __launch_bounds__(256) void k_part(const int* __restrict__ src, const int* __restrict__ dst,
                                              int* __restrict__ bcur, uint* __restrict__ pbuf,
                                              int e, int nb) {
    __shared__ int h[800];
    __shared__ int base_l[800];
    for (int t = threadIdx.x; t < nb; t += 256) h[t] = 0;
    __syncthreads();
    uint pk[10]; int bk[10]; int lp[10];
    int ibase = blockIdx.x * 2560 + threadIdx.x;
#pragma unroll
    for (int j = 0; j < 10; j++) {
        int i = ibase + j * 256;
        bk[j] = -1;
        if (i < e) {
            int s = src[i], d = dst[i];
            int b = d >> 7;
            bk[j] = b;
            pk[j] = ((uint)(d & 127) << 25) | (uint)s;
            lp[j] = atomicAdd(&h[b], 1);
        }
    }
    __syncthreads();
    for (int t = threadIdx.x; t < nb; t += 256) {
        int c = h[t];
        base_l[t] = c ? atomicAdd(&bcur[t], c) : 0;
    }
    __syncthreads();
#pragma unroll
    for (int j = 0; j < 10; j++) {
        if (bk[j] >= 0) pbuf[base_l[bk[j]] + lp[j]] = pk[j];
    }
}

// per-bucket fine sort: emits dinv, row_ptr, es_src
__global__ __launch_bounds__(256) void k_bsort(const uint* __restrict__ pbuf,
                                               const int* __restrict__ bbase,
                                               float* __restrict__ dinv,
                                               int* __restrict__ row_ptr,
                                               int* __restrict__ es_src, int n) {
    __shared__ int cl[128];
    __shared__ int cur[128];
    const int b = blockIdx.x;
    const int tid = threadIdx.x;
    const int ebeg = bbase[b], eend = bbase[b + 1];
    const int m = eend - ebeg;
    if (tid < 128) cl[tid] = 0;
    __syncthreads();
    for (int i = tid; i < m; i += 256) {
        uint p = pbuf[ebeg + i];
        atomicAdd(&cl[p >> 25], 1);
    }
    __syncthreads();
    int own = (tid < 128) ? cl[tid] : 0;
    for (int d = 1; d < 128; d <<= 1) {
        int v = 0;
        if (tid < 128 && tid >= d) v = cl[tid - d];
        __syncthreads();
        if (tid < 128 && tid >= d) cl[tid] += v;
        __syncthreads();
    }
    if (tid < 128) {
        int excl = cl[tid] - own;
        int node = b * 128 + tid;
        if (node < n) {
            dinv[node] = rsqrtf((float)(own + 1));   // deg incl. self-loop
            row_ptr[node] = ebeg + excl;
        }
        cur[tid] = excl;
    }
    __syncthreads();
    for (int i = tid; i < m; i += 256) {
        uint p = pbuf[ebeg + i];
        int dl = (int)(p >> 25);
        int pos = atomicAdd(&cur[dl], 1);
        es_src[ebeg + pos] = (int)(p & 0x1FFFFFFu);
    }
}

// ---- GEMM1 (MFMA bf16): h'[i] = bf16(dinv[i] * (x @ W1)[i]) -------------
__global__ __launch_bounds__(256) void k_gemm1(const float* __restrict__ x,
                                               const ushort_t* __restrict__ W1t,
                                               const float* __restrict__ dinv,
                                               ushort_t* __restrict__ h, int n) {
    __shared__ ushort_t As[64][72];
    __shared__ ushort_t Bs[128][72];
    const int tid  = threadIdx.x;
    const int w    = tid >> 6, lane = tid & 63;
    const int quad = lane >> 4, l16 = lane & 15;
    const int row0 = blockIdx.x * 64;

    float4v acc[8];
#pragma unroll
    for (int i = 0; i < 8; i++) acc[i] = (float4v)0.f;

    const int ar  = tid >> 2;
    const int akq = (tid & 3) * 16;
    const int br  = tid >> 1;
    const int bkq = (tid & 1) * 32;
    const int agrow = row0 + ar;
    const float* xp0 = &x[(size_t)agrow * 512];
    const ushort_t* wp0 = &W1t[(size_t)br * 512];

    for (int kb = 0; kb < 512; kb += 64) {
#pragma unroll
        for (int j = 0; j < 4; j++) {
            float4 v = make_float4(0.f, 0.f, 0.f, 0.f);
            if (agrow < n) v = *(const float4*)(xp0 + kb + akq + j * 4);
            ushort4 b;
            b.x = f2bf(v.x); b.y = f2bf(v.y); b.z = f2bf(v.z); b.w = f2bf(v.w);
            *(ushort4*)&As[ar][akq + j * 4] = b;
        }
#pragma unroll
        for (int j = 0; j < 8; j++) {
            *(ushort4*)&Bs[br][bkq + j * 4] = *(const ushort4*)(wp0 + kb + bkq + j * 4);
        }
        __syncthreads();
#pragma unroll
        for (int ks = 0; ks < 64; ks += 32) {
            short8 a = *(const short8*)&As[w * 16 + l16][ks + quad * 8];
#pragma unroll
            for (int ct = 0; ct < 8; ct++) {
                short8 b = *(const short8*)&Bs[ct * 16 + l16][ks + quad * 8];
                acc[ct] = __builtin_amdgcn_mfma_f32_16x16x32_bf16(a, b, acc[ct], 0, 0, 0);
            }
        }
        __syncthreads();
    }
#pragma unroll
    for (int r = 0; r < 4; r++) {
        int grow = row0 + w * 16 + quad * 4 + r;
        if (grow >= n) continue;
        float di = dinv[grow];
#pragma unroll
        for (int ct = 0; ct < 8; ct++) {
            int col = ct * 16 + l16;
            h[(size_t)grow * 128 + col] = f2bf(di * acc[ct][r]);
        }
    }
}

// ---- agg1: h1 = bf16(relu(dinv[node]*(h'[node]+Σ h'[src]) + b1)) --------
// one wave per node; 4 groups of 16 lanes; group gathers one 256 B row per
// dwordx4 instruction (4 edges in flight per instr, x2 unroll = 8).
__global__ __launch_bounds__(256) void k_agg1(const uint* __restrict__ h,
                                              const int* __restrict__ row_ptr,
                                              const int* __restrict__ es_src,
                                              const float* __restrict__ dinv,
                                              const float* __restrict__ b1,
                                              uint* __restrict__ h1, int n) {
    const int tid  = threadIdx.x;
    const int node = blockIdx.x * 4 + (tid >> 6);
    if (node >= n) return;
    const int lane = tid & 63;
    const int g4   = lane >> 4;     // group 0..3
    const int l16  = lane & 15;     // cols [l16*8, l16*8+8)
    const int k0 = row_ptr[node], k1 = row_ptr[node + 1];

    // self row: issue early, consume after reduce
    uint4 sv = *(const uint4*)&h[(size_t)node * 64 + l16 * 4];

    float acc[8];
#pragma unroll
    for (int i = 0; i < 8; i++) acc[i] = 0.f;

    int k = k0 + g4;
    for (; k + 4 < k1; k += 8) {        // 8 edges per wave iteration
        int s0 = es_src[k];
        int s1 = es_src[k + 4];
        uint4 v0 = *(const uint4*)&h[(size_t)s0 * 64 + l16 * 4];
        uint4 v1 = *(const uint4*)&h[(size_t)s1 * 64 + l16 * 4];
        acc8(acc, v0);
        acc8(acc, v1);
    }
    for (; k < k1; k += 4) {            // tail: 4 edges per iteration
        int s0 = es_src[k];
        uint4 v0 = *(const uint4*)&h[(size_t)s0 * 64 + l16 * 4];
        acc8(acc, v0);
    }

    // combine the 4 groups
#pragma unroll
    for (int i = 0; i < 8; i++) {
        acc[i] += __shfl_xor(acc[i], 16);
        acc[i] += __shfl_xor(acc[i], 32);
    }
    acc8(acc, sv);                      // add self once, post-reduce

    const float di = dinv[node];
    float4 ba = *(const float4*)&b1[l16 * 8];
    float4 bb = *(const float4*)&b1[l16 * 8 + 4];
    float r[8];
    r[0] = di * acc[0] + ba.x; r[1] = di * acc[1] + ba.y;
    r[2] = di * acc[2] + ba.z; r[3] = di * acc[3] + ba.w;
    r[4] = di * acc[4] + bb.x; r[5] = di * acc[5] + bb.y;
    r[6] = di * acc[6] + bb.z; r[7] = di * acc[7] + bb.w;
#pragma unroll
    for (int i = 0; i < 8; i++) r[i] = r[i] > 0.f ? r[i] : 0.f;

    if (g4 == 0) {
        uint4 o;
        o.x = pack2(r[0], r[1]); o.y = pack2(r[2], r[3]);
        o.z = pack2(r[4], r[5]); o.w = pack2(r[6], r[7]);
        *(uint4*)&h1[(size_t)node * 64 + l16 * 4] = o;
    }
}

// ---- GEMM2 (MFMA bf16): g[i] = bf16(dinv[i] * (h1 @ W2)[i]), [n,64] pad -
__global__ __launch_bounds__(256) void k_gemm2(const ushort_t* __restrict__ h1,
                                               const ushort_t* __restrict__ W2t,
                                               const float* __restrict__ dinv,
                                               ushort_t* __restrict__ g, int n) {
    __shared__ ushort_t As[64][136];
    __shared__ ushort_t Bs[48][136];
    const int tid  = threadIdx.x;
    const int w    = tid >> 6, lane = tid & 63;
    const int quad = lane >> 4, l16 = lane & 15;
    const int row0 = blockIdx.x * 64;

    {
        int ar = tid >> 2;
        int ak = (tid & 3) * 32;
        int grow = row0 + ar;
#pragma unroll
        for (int j = 0; j < 4; j++) {
            uint4 v = make_uint4(0, 0, 0, 0);
            if (grow < n) v = *(const uint4*)&h1[(size_t)grow * 128 + ak + j * 8];
            *(uint4*)&As[ar][ak + j * 8] = v;
        }
    }
    for (int i = tid; i < 768; i += 256) {
        int row = i >> 4, q = i & 15;
        *(uint4*)&Bs[row][q * 8] = *(const uint4*)&W2t[(size_t)row * 128 + q * 8];
    }
    __syncthreads();

    float4v acc[3];
#pragma unroll
    for (int i = 0; i < 3; i++) acc[i] = (float4v)0.f;
#pragma unroll
    for (int ks = 0; ks < 128; ks += 32) {
        short8 a = *(const short8*)&As[w * 16 + l16][ks + quad * 8];
#pragma unroll
        for (int ct = 0; ct < 3; ct++) {
            short8 b = *(const short8*)&Bs[ct * 16 + l16][ks + quad * 8];
            acc[ct] = __builtin_amdgcn_mfma_f32_16x16x32_bf16(a, b, acc[ct], 0, 0, 0);
        }
    }
#pragma unroll
    for (int r = 0; r < 4; r++) {
        int grow = row0 + w * 16 + quad * 4 + r;
        if (grow >= n) continue;
        float di = dinv[grow];
#pragma unroll
        for (int ct = 0; ct < 3; ct++) {
            int col = ct * 16 + l16;
            g[(size_t)grow * 64 + col] = f2bf(di * acc[ct][r]);
        }
        g[(size_t)grow * 64 + 48 + l16] = (ushort_t)0;   // zero pad cols 48..63
    }
}

// ---- agg2 + bias + log_softmax fused ------------------------------------
// one wave per node; 8 groups of 8 lanes; group gathers one 128 B row per
// dwordx4 instruction (8 edges in flight per instr, x2 unroll = 16).
__global__ __launch_bounds__(256) void k_agg2(const uint* __restrict__ g,
                                              const int* __restrict__ row_ptr,
                                              const int* __restrict__ es_src,
                                              const float* __restrict__ dinv,
                                              const float* __restrict__ b2,
                                              float* __restrict__ out1,
                                              float* __restrict__ out2, int n) {
    const int tid  = threadIdx.x;
    const int node = blockIdx.x * 4 + (tid >> 6);
    if (node >= n) return;
    const int lane = tid & 63;
    const int g8   = lane >> 3;     // group 0..7
    const int l8   = lane & 7;      // cols [l8*8, l8*8+8)
    const int k0 = row_ptr[node], k1 = row_ptr[node + 1];

    uint4 sv = *(const uint4*)&g[(size_t)node * 32 + l8 * 4];   // self, early

    float acc[8];
#pragma unroll
    for (int i = 0; i < 8; i++) acc[i] = 0.f;

    int k = k0 + g8;
    for (; k + 8 < k1; k += 16) {       // 16 edges per wave iteration
        int s0 = es_src[k];
        int s1 = es_src[k + 8];
        uint4 v0 = *(const uint4*)&g[(size_t)s0 * 32 + l8 * 4];
        uint4 v1 = *(const uint4*)&g[(size_t)s1 * 32 + l8 * 4];
        acc8(acc, v0);
        acc8(acc, v1);
    }
    for (; k < k1; k += 8) {            // tail: 8 edges per iteration
        int s0 = es_src[k];
        uint4 v0 = *(const uint4*)&g[(size_t)s0 * 32 + l8 * 4];
        acc8(acc, v0);
    }

    // combine the 8 groups
#pragma unroll
    for (int i = 0; i < 8; i++) {
        acc[i] += __shfl_xor(acc[i], 8);
        acc[i] += __shfl_xor(acc[i], 16);
        acc[i] += __shfl_xor(acc[i], 32);
    }
    acc8(acc, sv);                      // self, once

    const float di = dinv[node];
    float v[8];
    if (l8 < 5) {
        float4 ba = *(const float4*)&b2[l8 * 8];
        float4 bb = *(const float4*)&b2[l8 * 8 + 4];
        v[0] = di * acc[0] + ba.x; v[1] = di * acc[1] + ba.y;
        v[2] = di * acc[2] + ba.z; v[3] = di * acc[3] + ba.w;
        v[4] = di * acc[4] + bb.x; v[5] = di * acc[5] + bb.y;
        v[6] = di * acc[6] + bb.z; v[7] = di * acc[7] + bb.w;
    } else {
#pragma unroll
        for (int i = 0; i < 8; i++) v[i] = 0.f;
    }

    // log-softmax over the 40 real cols (lanes l8<5 hold 8 each)
    float m = -1e30f;
    if (l8 < 5) {
#pragma unroll
        for (int i = 0; i < 8; i++) m = fmaxf(m, v[i]);
    }
#pragma unroll
    for (int d = 1; d < 8; d <<= 1) m = fmaxf(m, __shfl_xor(m, d));
    float s = 0.f;
    if (l8 < 5) {
#pragma unroll
        for (int i = 0; i < 8; i++) s += expf(v[i] - m);
    }
#pragma unroll
    for (int d = 1; d < 8; d <<= 1) s += __shfl_xor(s, d);
    float ls = logf(s) + m;

    if (l8 < 5) {
        if (g8 == 0) {
            *(float4*)&out1[(size_t)node * 40 + l8 * 8]     = make_float4(v[0], v[1], v[2], v[3]);
            *(float4*)&out1[(size_t)node * 40 + l8 * 8 + 4] = make_float4(v[4], v[5], v[6], v[7]);
        } else if (g8 == 1) {
            *(float4*)&out2[(size_t)node * 40 + l8 * 8] =
                make_float4(v[0] - ls, v[1] - ls, v[2] - ls, v[3] - ls);
            *(float4*)&out2[(size_t)node * 40 + l8 * 8 + 4] =
                make_float4(v[4] - ls, v[5] - ls, v[6] - ls, v[7] - ls);
        }
    }
}

static inline size_t align4(size_t v) { return (v + 3) & ~(size_t)3; }

extern "C" void kernel_launch(void* const* d_in, const int* in_sizes, int n_in,
                              void* d_out, int out_size, void* d_ws, size_t ws_size,
                              hipStream_t stream) {
    const float* x  = (const float*)d_in[0];
    const int*   ei = (const int*)d_in[1];
    const float* W1 = (const float*)d_in[2];
    const float* b1 = (const float*)d_in[3];
    const float* W2 = (const float*)d_in[4];
    const float* b2 = (const float*)d_in[5];

    const int n = in_sizes[0] / 512;
    const int e = in_sizes[1] / 2;
    const int* src = ei;
    const int* dst = ei + e;
    const int NB = (n + 127) >> 7;           // buckets of 128 nodes (<=800)

    char* p = (char*)d_ws;
    int*      bcnt    = (int*)p;        p += align4(NB) * 4;
    int*      bbase   = (int*)p;        p += align4(NB + 1) * 4;
    int*      bcur    = (int*)p;        p += align4(NB) * 4;
    int*      row_ptr = (int*)p;        p += align4(n + 1) * 4;
    float*    dinv    = (float*)p;      p += align4(n) * 4;
    uint*     pbuf    = (uint*)p;       p += align4(e) * 4;
    int*      es_src  = (int*)p;        p += align4(e) * 4;
    ushort_t* W1t     = (ushort_t*)p;   p += (size_t)128 * 512 * 2;
    ushort_t* W2t     = (ushort_t*)p;   p += (size_t)48 * 128 * 2;
    ushort_t* h       = (ushort_t*)p;   p += (size_t)n * 128 * 2;   // h' bf16; g overlays
    ushort_t* h1      = (ushort_t*)p;   p += (size_t)n * 128 * 2;   // bf16
    ushort_t* g       = h;                                          // [n,64] bf16, 128 B rows
    float*    out1    = (float*)d_out;
    float*    out2    = out1 + (size_t)n * 40;

    const int B = 256;
    const int nblkA = (e + 2559) / 2560;

    // CSR build via 2-level counting sort (+ weight prep piggy-backed)
    hipMemsetAsync(bcnt, 0, (size_t)NB * 4, stream);
    k_bhist_wprep<<<nblkA + 280, B, 0, stream>>>(dst, bcnt, e, NB, nblkA, W1, W2, W1t, W2t);
    k_bscan<<<1, 256, 0, stream>>>(bcnt, bbase, bcur, row_ptr, NB, n, e);
    k_part<<<nblkA, B, 0, stream>>>(src, dst, bcur, pbuf, e, NB);
    k_bsort<<<NB, 256, 0, stream>>>(pbuf, bbase, dinv, row_ptr, es_src, n);

    // layer 1
    k_gemm1<<<(n + 63) / 64, 256, 0, stream>>>(x, W1t, dinv, h, n);
    k_agg1<<<(n + 3) / 4, 256, 0, stream>>>((const uint*)h, row_ptr, es_src, dinv, b1, (uint*)h1, n);

    // layer 2
    k_gemm2<<<(n + 63) / 64, 256, 0, stream>>>(h1, W2t, dinv, g, n);
    k_agg2<<<(n + 3) / 4, 256, 0, stream>>>((const uint*)g, row_ptr, es_src, dinv, b2, out1, out2, n);
}

// Round 3
// 518.442 us; speedup vs baseline: 1.1040x; 1.0321x over previous
//
#include <hip/hip_runtime.h>
#include <math.h>

// GCN 2-layer forward on MI355X — round 8.
//  Change vs round 7: CSR build and GEMM1 overlapped via fat block-role
//  kernels. gemm1 now emits RAW h = bf16(x@W1) (no dinv) so it has no
//  dependency on the CSR chain; a quarter of its blocks ride along with
//  each CSR stage (bhist/bscan/part/bsort). agg1 applies dinv[src] at
//  gather time (fma instead of add — free). bcnt zeroing folded into prep.
//  Dispatches: prep, d2(bhist+g1a), d3(bscan+g1b), d4(part+g1c),
//              d5(bsort+g1d), agg1, gemm2, agg2  = 8.

typedef unsigned int uint;
typedef unsigned short ushort_t;
using short8  = __attribute__((ext_vector_type(8))) short;
using float4v = __attribute__((ext_vector_type(4))) float;

__device__ __forceinline__ ushort_t f2bf(float f) {
    uint u = __float_as_uint(f);
    u += 0x7FFFu + ((u >> 16) & 1u);   // RNE
    return (ushort_t)(u >> 16);
}
__device__ __forceinline__ float2 unpack2(uint v) {
    return make_float2(__uint_as_float(v << 16), __uint_as_float(v & 0xFFFF0000u));
}
__device__ __forceinline__ uint pack2(float a, float b) {
    return (uint)f2bf(a) | ((uint)f2bf(b) << 16);
}
__device__ __forceinline__ void acc8(float* acc, uint4 v) {
    float2 a0 = unpack2(v.x), a1 = unpack2(v.y), a2 = unpack2(v.z), a3 = unpack2(v.w);
    acc[0] += a0.x; acc[1] += a0.y; acc[2] += a1.x; acc[3] += a1.y;
    acc[4] += a2.x; acc[5] += a2.y; acc[6] += a3.x; acc[7] += a3.y;
}
__device__ __forceinline__ void acc8s(float* acc, uint4 v, float d) {
    float2 a0 = unpack2(v.x), a1 = unpack2(v.y), a2 = unpack2(v.z), a3 = unpack2(v.w);
    acc[0] = fmaf(d, a0.x, acc[0]); acc[1] = fmaf(d, a0.y, acc[1]);
    acc[2] = fmaf(d, a1.x, acc[2]); acc[3] = fmaf(d, a1.y, acc[3]);
    acc[4] = fmaf(d, a2.x, acc[4]); acc[5] = fmaf(d, a2.y, acc[5]);
    acc[6] = fmaf(d, a3.x, acc[6]); acc[7] = fmaf(d, a3.y, acc[7]);
}

// ---- GEMM1 block body (RAW: no dinv) ------------------------------------
__device__ __forceinline__ void gemm1_block(int gb, const float* __restrict__ x,
                                            const ushort_t* __restrict__ W1t,
                                            ushort_t* __restrict__ h, int n) {
    __shared__ ushort_t As[64][72];
    __shared__ ushort_t Bs[128][72];
    const int tid  = threadIdx.x;
    const int w    = tid >> 6, lane = tid & 63;
    const int quad = lane >> 4, l16 = lane & 15;
    const int row0 = gb * 64;

    float4v acc[8];
#pragma unroll
    for (int i = 0; i < 8; i++) acc[i] = (float4v)0.f;

    const int ar  = tid >> 2;
    const int akq = (tid & 3) * 16;
    const int br  = tid >> 1;
    const int bkq = (tid & 1) * 32;
    const int agrow = row0 + ar;
    const float* xp0 = &x[(size_t)agrow * 512];
    const ushort_t* wp0 = &W1t[(size_t)br * 512];

    for (int kb = 0; kb < 512; kb += 64) {
#pragma unroll
        for (int j = 0; j < 4; j++) {
            float4 v = make_float4(0.f, 0.f, 0.f, 0.f);
            if (agrow < n) v = *(const float4*)(xp0 + kb + akq + j * 4);
            ushort4 b;
            b.x = f2bf(v.x); b.y = f2bf(v.y); b.z = f2bf(v.z); b.w = f2bf(v.w);
            *(ushort4*)&As[ar][akq + j * 4] = b;
        }
#pragma unroll
        for (int j = 0; j < 8; j++) {
            *(ushort4*)&Bs[br][bkq + j * 4] = *(const ushort4*)(wp0 + kb + bkq + j * 4);
        }
        __syncthreads();
#pragma unroll
        for (int ks = 0; ks < 64; ks += 32) {
            short8 a = *(const short8*)&As[w * 16 + l16][ks + quad * 8];
#pragma unroll
            for (int ct = 0; ct < 8; ct++) {
                short8 b = *(const short8*)&Bs[ct * 16 + l16][ks + quad * 8];
                acc[ct] = __builtin_amdgcn_mfma_f32_16x16x32_bf16(a, b, acc[ct], 0, 0, 0);
            }
        }
        __syncthreads();
    }
#pragma unroll
    for (int r = 0; r < 4; r++) {
        int grow = row0 + w * 16 + quad * 4 + r;
        if (grow >= n) continue;
#pragma unroll
        for (int ct = 0; ct < 8; ct++) {
            int col = ct * 16 + l16;
            h[(size_t)grow * 128 + col] = f2bf(acc[ct][r]);
        }
    }
}

// ---- prep: W1t/W2t bf16 transpose + bcnt zero ---------------------------
__global__ __launch_bounds__(256) void k_prep(const float* __restrict__ W1,
                                              const float* __restrict__ W2,
                                              ushort_t* __restrict__ W1t,
                                              ushort_t* __restrict__ W2t,
                                              int* __restrict__ bcnt, int nb) {
    int idx = blockIdx.x * 256 + threadIdx.x;
    if (idx < 65536) {
        int nn = idx >> 9, k = idx & 511;
        W1t[idx] = f2bf(W1[(size_t)k * 128 + nn]);
    } else if (idx < 71680) {
        int j = idx - 65536;
        int c = j >> 7, k = j & 127;
        W2t[j] = (c < 40) ? f2bf(W2[(size_t)k * 40 + c]) : (ushort_t)0;
    } else {
        int j = idx - 71680;
        if (j < nb) bcnt[j] = 0;
    }
}

// ---- D2: bhist (blocks < nblkA)  ∪  gemm1 chunk -------------------------
__global__ __launch_bounds__(256) void k_d2(const int* __restrict__ dst,
                                            int* __restrict__ bcnt, int e, int nb, int nblkA,
                                            const float* __restrict__ x,
                                            const ushort_t* __restrict__ W1t,
                                            ushort_t* __restrict__ h, int n, int goff) {
    if ((int)blockIdx.x >= nblkA) {
        gemm1_block((int)blockIdx.x - nblkA + goff, x, W1t, h, n);
        return;
    }
    __shared__ int sh[800];
    for (int t = threadIdx.x; t < nb; t += 256) sh[t] = 0;
    __syncthreads();
    int ibase = blockIdx.x * 2560 + threadIdx.x;
#pragma unroll
    for (int j = 0; j < 10; j++) {
        int i = ibase + j * 256;
        if (i < e) atomicAdd(&sh[dst[i] >> 7], 1);
    }
    __syncthreads();
    for (int t = threadIdx.x; t < nb; t += 256) {
        int c = sh[t];
        if (c) atomicAdd(&bcnt[t], c);
    }
}

// ---- D3: bscan (block 0)  ∪  gemm1 chunk --------------------------------
__global__ __launch_bounds__(256) void k_d3(const int* __restrict__ bcnt, int* __restrict__ bbase,
                                            int* __restrict__ bcur, int* __restrict__ row_ptr,
                                            int nb, int n, int e,
                                            const float* __restrict__ x,
                                            const ushort_t* __restrict__ W1t,
                                            ushort_t* __restrict__ h, int goff) {
    if (blockIdx.x > 0) {
        gemm1_block((int)blockIdx.x - 1 + goff, x, W1t, h, n);
        return;
    }
    __shared__ int sd[256];
    int t = threadIdx.x;
    int base = t * 4;
    int v[4];
#pragma unroll
    for (int j = 0; j < 4; j++) v[j] = (base + j < nb) ? bcnt[base + j] : 0;
    int s0 = v[0], s1 = s0 + v[1], s2 = s1 + v[2], s3 = s2 + v[3];
    sd[t] = s3;
    __syncthreads();
    for (int d = 1; d < 256; d <<= 1) {
        int xv = (t >= d) ? sd[t - d] : 0;
        __syncthreads();
        sd[t] += xv;
        __syncthreads();
    }
    int excl = sd[t] - s3;
    int pre0 = excl, pre1 = excl + s0, pre2 = excl + s1, pre3 = excl + s2;
    if (base + 0 < nb) { bbase[base + 0] = pre0; bcur[base + 0] = pre0; }
    if (base + 1 < nb) { bbase[base + 1] = pre1; bcur[base + 1] = pre1; }
    if (base + 2 < nb) { bbase[base + 2] = pre2; bcur[base + 2] = pre2; }
    if (base + 3 < nb) { bbase[base + 3] = pre3; bcur[base + 3] = pre3; }
    if (t == 255) bbase[nb] = excl + s3;   // == e
    if (t == 0) row_ptr[n] = e;
}

// ---- D4: part (blocks < nblkA)  ∪  gemm1 chunk --------------------------
__global__ __launch_bounds__(256) void k_d4(const int* __restrict__ src, const int* __restrict__ dst,
                                            int* __restrict__ bcur, uint* __restrict__ pbuf,
                                            int e, int nb, int nblkA,
                                            const float* __restrict__ x,
                                            const ushort_t* __restrict__ W1t,
                                            ushort_t* __restrict__ h, int n, int goff) {
    if ((int)blockIdx.x >= nblkA) {
        gemm1_block((int)blockIdx.x - nblkA + goff, x, W1t, h, n);
        return;
    }
    __shared__ int sh[800];
    __shared__ int base_l[800];
    for (int t = threadIdx.x; t < nb; t += 256) sh[t] = 0;
    __syncthreads();
    uint pk[10]; int bk[10]; int lp[10];
    int ibase = blockIdx.x * 2560 + threadIdx.x;
#pragma unroll
    for (int j = 0; j < 10; j++) {
        int i = ibase + j * 256;
        bk[j] = -1;
        if (i < e) {
            int s = src[i], d = dst[i];
            int b = d >> 7;
            bk[j] = b;
            pk[j] = ((uint)(d & 127) << 25) | (uint)s;
            lp[j] = atomicAdd(&sh[b], 1);
        }
    }
    __syncthreads();
    for (int t = threadIdx.x; t < nb; t += 256) {
        int c = sh[t];
        base_l[t] = c ? atomicAdd(&bcur[t], c) : 0;
    }
    __syncthreads();
#pragma unroll
    for (int j = 0; j < 10; j++) {
        if (bk[j] >= 0) pbuf[base_l[bk[j]] + lp[j]] = pk[j];
    }
}

// ---- D5: bsort (blocks < NB)  ∪  gemm1 chunk ----------------------------
__global__ __launch_bounds__(256) void k_d5(const uint* __restrict__ pbuf,
                                            const int* __restrict__ bbase,
                                            float* __restrict__ dinv,
                                            int* __restrict__ row_ptr,
                                            int* __restrict__ es_src, int n, int nb,
                                            const float* __restrict__ x,
                                            const ushort_t* __restrict__ W1t,
                                            ushort_t* __restrict__ h, int goff) {
    if ((int)blockIdx.x >= nb) {
        gemm1_block((int)blockIdx.x - nb + goff, x, W1t, h, n);
        return;
    }
    __shared__ int cl[128];
    __shared__ int cur[128];
    const int b = blockIdx.x;
    const int tid = threadIdx.x;
    const int ebeg = bbase[b], eend = bbase[b + 1];
    const int m = eend - ebeg;
    if (tid < 128) cl[tid] = 0;
    __syncthreads();
    for (int i = tid; i < m; i += 256) {
        uint p = pbuf[ebeg + i];
        atomicAdd(&cl[p >> 25], 1);
    }
    __syncthreads();
    int own = (tid < 128) ? cl[tid] : 0;
    for (int d = 1; d < 128; d <<= 1) {
        int v = 0;
        if (tid < 128 && tid >= d) v = cl[tid - d];
        __syncthreads();
        if (tid < 128 && tid >= d) cl[tid] += v;
        __syncthreads();
    }
    if (tid < 128) {
        int excl = cl[tid] - own;
        int node = b * 128 + tid;
        if (node < n) {
            dinv[node] = rsqrtf((float)(own + 1));   // deg incl. self-loop
            row_ptr[node] = ebeg + excl;
        }
        cur[tid] = excl;
    }
    __syncthreads();
    for (int i = tid; i < m; i += 256) {
        uint p = pbuf[ebeg + i];
        int dl = (int)(p >> 25);
        int pos = atomicAdd(&cur[dl], 1);
        es_src[ebeg + pos] = (int)(p & 0x1FFFFFFu);
    }
}

// ---- agg1: h1 = bf16(relu(dinv[i]*(dinv[i]h[i]+Σ dinv[s]h[s]) + b1)) ----
// one wave per node; 4 groups of 16 lanes; dwordx4 row gather, x2 unroll.
// dinv[src] applied at gather time (fma).
__global__ __launch_bounds__(256) void k_agg1(const uint* __restrict__ h,
                                              const int* __restrict__ row_ptr,
                                              const int* __restrict__ es_src,
                                              const float* __restrict__ dinv,
                                              const float* __restrict__ b1,
                                              uint* __restrict__ h1, int n) {
    const int tid  = threadIdx.x;
    const int node = blockIdx.x * 4 + (tid >> 6);
    if (node >= n) return;
    const int lane = tid & 63;
    const int g4   = lane >> 4;     // group 0..3
    const int l16  = lane & 15;     // cols [l16*8, l16*8+8)
    const int k0 = row_ptr[node], k1 = row_ptr[node + 1];
    const float di = dinv[node];

    uint4 sv = *(const uint4*)&h[(size_t)node * 64 + l16 * 4];   // self, early

    float acc[8];
#pragma unroll
    for (int i = 0; i < 8; i++) acc[i] = 0.f;

    int k = k0 + g4;
    for (; k + 4 < k1; k += 8) {        // 8 edges per wave iteration
        int s0 = es_src[k];
        int s1 = es_src[k + 4];
        float d0 = dinv[s0], d1 = dinv[s1];
        uint4 v0 = *(const uint4*)&h[(size_t)s0 * 64 + l16 * 4];
        uint4 v1 = *(const uint4*)&h[(size_t)s1 * 64 + l16 * 4];
        acc8s(acc, v0, d0);
        acc8s(acc, v1, d1);
    }
    for (; k < k1; k += 4) {            // tail: 4 edges per iteration
        int s0 = es_src[k];
        float d0 = dinv[s0];
        uint4 v0 = *(const uint4*)&h[(size_t)s0 * 64 + l16 * 4];
        acc8s(acc, v0, d0);
    }

    // combine the 4 groups
#pragma unroll
    for (int i = 0; i < 8; i++) {
        acc[i] += __shfl_xor(acc[i], 16);
        acc[i] += __shfl_xor(acc[i], 32);
    }
    acc8s(acc, sv, di);                 // self term, once

    float4 ba = *(const float4*)&b1[l16 * 8];
    float4 bb = *(const float4*)&b1[l16 * 8 + 4];
    float r[8];
    r[0] = di * acc[0] + ba.x; r[1] = di * acc[1] + ba.y;
    r[2] = di * acc[2] + ba.z; r[3] = di * acc[3] + ba.w;
    r[4] = di * acc[4] + bb.x; r[5] = di * acc[5] + bb.y;
    r[6] = di * acc[6] + bb.z; r[7] = di * acc[7] + bb.w;
#pragma unroll
    for (int i = 0; i < 8; i++) r[i] = r[i] > 0.f ? r[i] : 0.f;

    if (g4 == 0) {
        uint4 o;
        o.x = pack2(r[0], r[1]); o.y = pack2(r[2], r[3]);
        o.z = pack2(r[4], r[5]); o.w = pack2(r[6], r[7]);
        *(uint4*)&h1[(size_t)node * 64 + l16 * 4] = o;
    }
}

// ---- GEMM2 (MFMA bf16): g[i] = bf16(dinv[i] * (h1 @ W2)[i]), [n,64] pad -
__global__ __launch_bounds__(256) void k_gemm2(const ushort_t* __restrict__ h1,
                                               const ushort_t* __restrict__ W2t,
                                               const float* __restrict__ dinv,
                                               ushort_t* __restrict__ g, int n) {
    __shared__ ushort_t As[64][136];
    __shared__ ushort_t Bs[48][136];
    const int tid  = threadIdx.x;
    const int w    = tid >> 6, lane = tid & 63;
    const int quad = lane >> 4, l16 = lane & 15;
    const int row0 = blockIdx.x * 64;

    {
        int ar = tid >> 2;
        int ak = (tid & 3) * 32;
        int grow = row0 + ar;
#pragma unroll
        for (int j = 0; j < 4; j++) {
            uint4 v = make_uint4(0, 0, 0, 0);
            if (grow < n) v = *(const uint4*)&h1[(size_t)grow * 128 + ak + j * 8];
            *(uint4*)&As[ar][ak + j * 8] = v;
        }
    }
    for (int i = tid; i < 768; i += 256) {
        int row = i >> 4, q = i & 15;
        *(uint4*)&Bs[row][q * 8] = *(const uint4*)&W2t[(size_t)row * 128 + q * 8];
    }
    __syncthreads();

    float4v acc[3];
#pragma unroll
    for (int i = 0; i < 3; i++) acc[i] = (float4v)0.f;
#pragma unroll
    for (int ks = 0; ks < 128; ks += 32) {
        short8 a = *(const short8*)&As[w * 16 + l16][ks + quad * 8];
#pragma unroll
        for (int ct = 0; ct < 3; ct++) {
            short8 b = *(const short8*)&Bs[ct * 16 + l16][ks + quad * 8];
            acc[ct] = __builtin_amdgcn_mfma_f32_16x16x32_bf16(a, b, acc[ct], 0, 0, 0);
        }
    }
#pragma unroll
    for (int r = 0; r < 4; r++) {
        int grow = row0 + w * 16 + quad * 4 + r;
        if (grow >= n) continue;
        float di = dinv[grow];
#pragma unroll
        for (int ct = 0; ct < 3; ct++) {
            int col = ct * 16 + l16;
            g[(size_t)grow * 64 + col] = f2bf(di * acc[ct][r]);
        }
        g[(size_t)grow * 64 + 48 + l16] = (ushort_t)0;   // zero pad cols 48..63
    }
}

// ---- agg2 + bias + log_softmax fused ------------------------------------
// one wave per node; 8 groups of 8 lanes; dwordx4 row gather, x2 unroll.
__global__ __launch_bounds__(256) void k_agg2(const uint* __restrict__ g,
                                              const int* __restrict__ row_ptr,
                                              const int* __restrict__ es_src,
                                              const float* __restrict__ dinv,
                                              const float* __restrict__ b2,
                                              float* __restrict__ out1,
                                              float* __restrict__ out2, int n) {
    const int tid  = threadIdx.x;
    const int node = blockIdx.x * 4 + (tid >> 6);
    if (node >= n) return;
    const int lane = tid & 63;
    const int g8   = lane >> 3;     // group 0..7
    const int l8   = lane & 7;      // cols [l8*8, l8*8+8)
    const int k0 = row_ptr[node], k1 = row_ptr[node + 1];

    uint4 sv = *(const uint4*)&g[(size_t)node * 32 + l8 * 4];   // self, early

    float acc[8];
#pragma unroll
    for (int i = 0; i < 8; i++) acc[i] = 0.f;

    int k = k0 + g8;
    for (; k + 8 < k1; k += 16) {       // 16 edges per wave iteration
        int s0 = es_src[k];
        int s1 = es_src[k + 8];
        uint4 v0 = *(const uint4*)&g[(size_t)s0 * 32 + l8 * 4];
        uint4 v1 = *(const uint4*)&g[(size_t)s1 * 32 + l8 * 4];
        acc8(acc, v0);
        acc8(acc, v1);
    }
    for (; k < k1; k += 8) {            // tail: 8 edges per iteration
        int s0 = es_src[k];
        uint4 v0 = *(const uint4*)&g[(size_t)s0 * 32 + l8 * 4];
        acc8(acc, v0);
    }

    // combine the 8 groups
#pragma unroll
    for (int i = 0; i < 8; i++) {
        acc[i] += __shfl_xor(acc[i], 8);
        acc[i] += __shfl_xor(acc[i], 16);
        acc[i] += __shfl_xor(acc[i], 32);
    }
    acc8(acc, sv);                      // self, once

    const float di = dinv[node];
    float v[8];
    if (l8 < 5) {
        float4 ba = *(const float4*)&b2[l8 * 8];
        float4 bb = *(const float4*)&b2[l8 * 8 + 4];
        v[0] = di * acc[0] + ba.x; v[1] = di * acc[1] + ba.y;
        v[2] = di * acc[2] + ba.z; v[3] = di * acc[3] + ba.w;
        v[4] = di * acc[4] + bb.x; v[5] = di * acc[5] + bb.y;
        v[6] = di * acc[6] + bb.z; v[7] = di * acc[7] + bb.w;
    } else {
#pragma unroll
        for (int i = 0; i < 8; i++) v[i] = 0.f;
    }

    // log-softmax over the 40 real cols (lanes l8<5 hold 8 each)
    float m = -1e30f;
    if (l8 < 5) {
#pragma unroll
        for (int i = 0; i < 8; i++) m = fmaxf(m, v[i]);
    }
#pragma unroll
    for (int d = 1; d < 8; d <<= 1) m = fmaxf(m, __shfl_xor(m, d));
    float s = 0.f;
    if (l8 < 5) {
#pragma unroll
        for (int i = 0; i < 8; i++) s += expf(v[i] - m);
    }
#pragma unroll
    for (int d = 1; d < 8; d <<= 1) s += __shfl_xor(s, d);
    float ls = logf(s) + m;

    if (l8 < 5) {
        if (g8 == 0) {
            *(float4*)&out1[(size_t)node * 40 + l8 * 8]     = make_float4(v[0], v[1], v[2], v[3]);
            *(float4*)&out1[(size_t)node * 40 + l8 * 8 + 4] = make_float4(v[4], v[5], v[6], v[7]);
        } else if (g8 == 1) {
            *(float4*)&out2[(size_t)node * 40 + l8 * 8] =
                make_float4(v[0] - ls, v[1] - ls, v[2] - ls, v[3] - ls);
            *(float4*)&out2[(size_t)node * 40 + l8 * 8 + 4] =
                make_float4(v[4] - ls, v[5] - ls, v[6] - ls, v[7] - ls);
        }
    }
}

static inline size_t align4(size_t v) { return (v + 3) & ~(size_t)3; }

extern "C" void kernel_launch(void* const* d_in, const int* in_sizes, int n_in,
                              void* d_out, int out_size, void* d_ws, size_t ws_size,
                              hipStream_t stream) {
    const float* x  = (const float*)d_in[0];
    const int*   ei = (const int*)d_in[1];
    const float* W1 = (const float*)d_in[2];
    const float* b1 = (const float*)d_in[3];
    const float* W2 = (const float*)d_in[4];
    const float* b2 = (const float*)d_in[5];

    const int n = in_sizes[0] / 512;
    const int e = in_sizes[1] / 2;
    const int* src = ei;
    const int* dst = ei + e;
    const int NB = (n + 127) >> 7;           // buckets of 128 nodes (<=800)

    char* p = (char*)d_ws;
    int*      bcnt    = (int*)p;        p += align4(NB) * 4;
    int*      bbase   = (int*)p;        p += align4(NB + 1) * 4;
    int*      bcur    = (int*)p;        p += align4(NB) * 4;
    int*      row_ptr = (int*)p;        p += align4(n + 1) * 4;
    float*    dinv    = (float*)p;      p += align4(n) * 4;
    uint*     pbuf    = (uint*)p;       p += align4(e) * 4;
    int*      es_src  = (int*)p;        p += align4(e) * 4;
    ushort_t* W1t     = (ushort_t*)p;   p += (size_t)128 * 512 * 2;
    ushort_t* W2t     = (ushort_t*)p;   p += (size_t)48 * 128 * 2;
    ushort_t* h       = (ushort_t*)p;   p += (size_t)n * 128 * 2;   // h' bf16; g overlays
    ushort_t* h1      = (ushort_t*)p;   p += (size_t)n * 128 * 2;   // bf16
    ushort_t* g       = h;                                          // [n,64] bf16, 128 B rows
    float*    out1    = (float*)d_out;
    float*    out2    = out1 + (size_t)n * 40;

    const int B = 256;
    const int nblkA = (e + 2559) / 2560;
    const int NG = (n + 63) / 64;           // gemm1 blocks total
    const int c  = (NG + 3) / 4;            // chunk size
    const int c3 = NG - 3 * c;              // last chunk

    // prep (weights + bcnt zero)
    k_prep<<<(71680 + NB + 255) / 256, B, 0, stream>>>(W1, W2, W1t, W2t, bcnt, NB);

    // CSR build overlapped with gemm1 quarters
    k_d2<<<nblkA + c, B, 0, stream>>>(dst, bcnt, e, NB, nblkA, x, W1t, h, n, 0);
    k_d3<<<1 + c, B, 0, stream>>>(bcnt, bbase, bcur, row_ptr, NB, n, e, x, W1t, h, c);
    k_d4<<<nblkA + c, B, 0, stream>>>(src, dst, bcur, pbuf, e, NB, nblkA, x, W1t, h, n, 2 * c);
    k_d5<<<NB + c3, B, 0, stream>>>(pbuf, bbase, dinv, row_ptr, es_src, n, NB, x, W1t, h, 3 * c);

    // layer 1 aggregation (dinv[src] applied at gather)
    k_agg1<<<(n + 3) / 4, B, 0, stream>>>((const uint*)h, row_ptr, es_src, dinv, b1, (uint*)h1, n);

    // layer 2
    k_gemm2<<<(n + 63) / 64, B, 0, stream>>>(h1, W2t, dinv, g, n);
    k_agg2<<<(n + 3) / 4, B, 0, stream>>>((const uint*)g, row_ptr, es_src, dinv, b2, out1, out2, n);
}